// Round 3
// baseline (91.092 us; speedup 1.0000x reference)
//
#include <hip/hip_runtime.h>
#include <math.h>

namespace {

constexpr int NOUT   = 10240;
constexpr int OPB    = 4;      // coarse nodes per block
constexpr int NIJ    = 16;     // so*si receptive field
constexpr int NPD    = 16;     // n_phi * n_dist
constexpr int QH     = 8;      // q per thread (NPD/2)
constexpr int NC     = 32;     // channels
constexpr int NIN    = NOUT * NIJ;

__device__ __forceinline__ void fma4(float4& a, float s, const float4& v) {
    a.x = fmaf(s, v.x, a.x);
    a.y = fmaf(s, v.y, a.y);
    a.z = fmaf(s, v.z, a.z);
    a.w = fmaf(s, v.w, a.w);
}

__global__ __launch_bounds__(256, 8) void polnorm_kernel(
    const float* __restrict__ x,        // (B, NIN, 1, 1, NC)
    const float* __restrict__ cx,       // (1, NOUT, 4, 4)
    const float* __restrict__ cy,       // (1, NOUT, 4, 4)
    const float* __restrict__ phis,     // (4,)
    const float* __restrict__ dists_p,  // (4,)
    const float* __restrict__ sigma_p,  // (1,)
    float* __restrict__ out)            // (B, NOUT, 1, 4, 4, 1, NC)
{
    __shared__ float s_w[OPB * NPD * NIJ];   // raw weights [o][pd][ij]
    __shared__ float s_inv[OPB * NPD];       // 1/(sum_ij w + 1e-20)

    const int t = threadIdx.x;
    const int o_base = blockIdx.x * OPB;

    // ---------------- fill phase: w + normalization factors ----------------
    {
        const int pd = t >> 4;        // 0..15
        const int ij = t & 15;        // 0..15
        const int p = pd >> 2, d = pd & 3;

        const float dist = 2.0f / (1.0f + expf(-dists_p[d]));  // 2*sigmoid
        const float phi  = phis[p];
        const float mux  = cosf(phi) * dist;
        const float muy  = sinf(phi) * dist;
        float sg = 2.0f / (1.0f + expf(-sigma_p[0]));
        sg = fmaxf(sg, 1e-10f);
        const float coef = -0.5f / (sg * sg);

        #pragma unroll
        for (int k = 0; k < OPB; ++k) {
            const int o = o_base + k;
            const float dx = cx[o * NIJ + ij] - mux;
            const float dy = cy[o * NIJ + ij] - muy;
            const float w = expf(coef * (dx * dx + dy * dy));
            s_w[k * (NPD * NIJ) + t] = w;   // [o][pd][ij], ij contiguous
            // sum over ij = reduction over 16 consecutive lanes
            float s = w;
            s += __shfl_xor(s, 1);
            s += __shfl_xor(s, 2);
            s += __shfl_xor(s, 4);
            s += __shfl_xor(s, 8);
            if (ij == 0) s_inv[k * NPD + pd] = 1.0f / (s + 1e-20f);
        }
    }
    __syncthreads();

    // ---------------- main phase: 8 q per thread, acc-resident ----------------
    const int c4      = t & 7;        // float4 lane within 32 channels
    const int b       = (t >> 3) & 3; // 0..3
    const int qh      = (t >> 5) & 1; // which half of the 16 q
    const int o_local = t >> 6;       // 0..3  (one o per wave)
    const int o       = o_base + o_local;

    const float4* xp = reinterpret_cast<const float4*>(
        x + ((size_t)b * NIN + (size_t)o * NIJ) * NC) + c4;
    const float* wrow   = s_w + o_local * (NPD * NIJ) + qh * (QH * NIJ);
    const float* invrow = s_inv + o_local * NPD + qh * QH;

    float4 acc[QH];
    #pragma unroll
    for (int q = 0; q < QH; ++q) acc[q] = make_float4(0.f, 0.f, 0.f, 0.f);

    // k outer in chunks of 4, q inner (acc live).
    #pragma unroll
    for (int kk = 0; kk < NIJ / 4; ++kk) {
        const float4 xv0 = xp[(size_t)(4 * kk + 0) * (NC / 4)];
        const float4 xv1 = xp[(size_t)(4 * kk + 1) * (NC / 4)];
        const float4 xv2 = xp[(size_t)(4 * kk + 2) * (NC / 4)];
        const float4 xv3 = xp[(size_t)(4 * kk + 3) * (NC / 4)];
        #pragma unroll
        for (int q = 0; q < QH; ++q) {
            const float4 w = *reinterpret_cast<const float4*>(wrow + q * NIJ + 4 * kk);
            fma4(acc[q], w.x, xv0);
            fma4(acc[q], w.y, xv1);
            fma4(acc[q], w.z, xv2);
            fma4(acc[q], w.w, xv3);
        }
    }

    float4* op = reinterpret_cast<float4*>(
        out + ((size_t)b * NOUT + o) * (size_t)(NPD * NC) + (size_t)qh * (QH * NC)) + c4;
    #pragma unroll
    for (int q = 0; q < QH; ++q) {
        const float inv = invrow[q];
        float4 a = acc[q];
        a.x *= inv; a.y *= inv; a.z *= inv; a.w *= inv;
        op[(size_t)q * (NC / 4)] = a;
    }
}

} // namespace

extern "C" void kernel_launch(void* const* d_in, const int* in_sizes, int n_in,
                              void* d_out, int out_size, void* d_ws, size_t ws_size,
                              hipStream_t stream) {
    const float* x  = (const float*)d_in[0];
    const float* cx = (const float*)d_in[1];
    const float* cy = (const float*)d_in[2];
    const float* ph = (const float*)d_in[3];
    const float* dp = (const float*)d_in[4];
    const float* sp = (const float*)d_in[5];
    float* out = (float*)d_out;

    dim3 grid(NOUT / OPB);
    dim3 block(256);
    hipLaunchKernelGGL(polnorm_kernel, grid, block, 0, stream,
                       x, cx, cy, ph, dp, sp, out);
}

// Round 4
// 33.683 us; speedup vs baseline: 2.7044x; 2.7044x over previous
//
#include <hip/hip_runtime.h>
#include <math.h>

namespace {

constexpr int NOUT   = 10240;
constexpr int OPB    = 4;      // coarse nodes per block
constexpr int NIJ    = 16;     // so*si receptive field
constexpr int NPD    = 16;     // n_phi * n_dist
constexpr int QH     = 8;      // q per thread (NPD/2)
constexpr int NC     = 32;     // channels
constexpr int NIN    = NOUT * NIJ;

__device__ __forceinline__ void fma4(float4& a, float s, const float4& v) {
    a.x = fmaf(s, v.x, a.x);
    a.y = fmaf(s, v.y, a.y);
    a.z = fmaf(s, v.z, a.z);
    a.w = fmaf(s, v.w, a.w);
}

__global__ __launch_bounds__(256) void polnorm_kernel(
    const float* __restrict__ x,        // (B, NIN, 1, 1, NC)
    const float* __restrict__ cx,       // (1, NOUT, 4, 4)
    const float* __restrict__ cy,       // (1, NOUT, 4, 4)
    const float* __restrict__ phis,     // (4,)
    const float* __restrict__ dists_p,  // (4,)
    const float* __restrict__ sigma_p,  // (1,)
    float* __restrict__ out)            // (B, NOUT, 1, 4, 4, 1, NC)
{
    __shared__ float s_w[OPB * NPD * NIJ];   // raw weights [o][pd][ij]
    __shared__ float s_inv[OPB * NPD];       // 1/(sum_ij w + 1e-20)

    const int t = threadIdx.x;
    const int o_base = blockIdx.x * OPB;

    // ---------------- fill phase: w + normalization factors ----------------
    {
        const int pd = t >> 4;        // 0..15
        const int ij = t & 15;        // 0..15
        const int p = pd >> 2, d = pd & 3;

        const float dist = 2.0f / (1.0f + expf(-dists_p[d]));  // 2*sigmoid
        const float phi  = phis[p];
        const float mux  = cosf(phi) * dist;
        const float muy  = sinf(phi) * dist;
        float sg = 2.0f / (1.0f + expf(-sigma_p[0]));
        sg = fmaxf(sg, 1e-10f);
        const float coef = -0.5f / (sg * sg);

        #pragma unroll
        for (int k = 0; k < OPB; ++k) {
            const int o = o_base + k;
            const float dx = cx[o * NIJ + ij] - mux;
            const float dy = cy[o * NIJ + ij] - muy;
            const float w = expf(coef * (dx * dx + dy * dy));
            s_w[k * (NPD * NIJ) + t] = w;   // [o][pd][ij], ij contiguous
            // sum over ij = reduction over 16 consecutive lanes
            float s = w;
            s += __shfl_xor(s, 1);
            s += __shfl_xor(s, 2);
            s += __shfl_xor(s, 4);
            s += __shfl_xor(s, 8);
            if (ij == 0) s_inv[k * NPD + pd] = 1.0f / (s + 1e-20f);
        }
    }
    __syncthreads();

    // ---------------- main phase: 8 q per thread, acc-resident ----------------
    const int c4      = t & 7;        // float4 lane within 32 channels
    const int b       = (t >> 3) & 3; // 0..3
    const int qh      = (t >> 5) & 1; // which half of the 16 q
    const int o_local = t >> 6;       // 0..3  (one o per wave)
    const int o       = o_base + o_local;

    const float4* xp = reinterpret_cast<const float4*>(
        x + ((size_t)b * NIN + (size_t)o * NIJ) * NC) + c4;
    const float* wrow   = s_w + o_local * (NPD * NIJ) + qh * (QH * NIJ);
    const float* invrow = s_inv + o_local * NPD + qh * QH;

    float4 acc[QH];
    #pragma unroll
    for (int q = 0; q < QH; ++q) acc[q] = make_float4(0.f, 0.f, 0.f, 0.f);

    // k outer in chunks of 4, q inner (acc live).
    #pragma unroll
    for (int kk = 0; kk < NIJ / 4; ++kk) {
        const float4 xv0 = xp[(size_t)(4 * kk + 0) * (NC / 4)];
        const float4 xv1 = xp[(size_t)(4 * kk + 1) * (NC / 4)];
        const float4 xv2 = xp[(size_t)(4 * kk + 2) * (NC / 4)];
        const float4 xv3 = xp[(size_t)(4 * kk + 3) * (NC / 4)];
        #pragma unroll
        for (int q = 0; q < QH; ++q) {
            const float4 w = *reinterpret_cast<const float4*>(wrow + q * NIJ + 4 * kk);
            fma4(acc[q], w.x, xv0);
            fma4(acc[q], w.y, xv1);
            fma4(acc[q], w.z, xv2);
            fma4(acc[q], w.w, xv3);
        }
    }

    float4* op = reinterpret_cast<float4*>(
        out + ((size_t)b * NOUT + o) * (size_t)(NPD * NC) + (size_t)qh * (QH * NC)) + c4;
    #pragma unroll
    for (int q = 0; q < QH; ++q) {
        const float inv = invrow[q];
        float4 a = acc[q];
        a.x *= inv; a.y *= inv; a.z *= inv; a.w *= inv;
        op[(size_t)q * (NC / 4)] = a;
    }
}

} // namespace

extern "C" void kernel_launch(void* const* d_in, const int* in_sizes, int n_in,
                              void* d_out, int out_size, void* d_ws, size_t ws_size,
                              hipStream_t stream) {
    const float* x  = (const float*)d_in[0];
    const float* cx = (const float*)d_in[1];
    const float* cy = (const float*)d_in[2];
    const float* ph = (const float*)d_in[3];
    const float* dp = (const float*)d_in[4];
    const float* sp = (const float*)d_in[5];
    float* out = (float*)d_out;

    dim3 grid(NOUT / OPB);
    dim3 block(256);
    hipLaunchKernelGGL(polnorm_kernel, grid, block, 0, stream,
                       x, cx, cy, ph, dp, sp, out);
}

// Round 5
// 32.844 us; speedup vs baseline: 2.7735x; 1.0255x over previous
//
#include <hip/hip_runtime.h>
#include <math.h>

namespace {

constexpr int NOUT = 10240;
constexpr int OPB  = 4;      // coarse nodes per block
constexpr int NIJ  = 16;     // so*si receptive field
constexpr int NPD  = 16;     // n_phi * n_dist
constexpr int NC   = 32;     // channels
constexpr int NIN  = NOUT * NIJ;
constexpr int WPAD = 20;     // padded ij-stride for s_w (bank-conflict-free float4 reads)

__device__ __forceinline__ void fma4(float4& a, float s, const float4& v) {
    a.x = fmaf(s, v.x, a.x);
    a.y = fmaf(s, v.y, a.y);
    a.z = fmaf(s, v.z, a.z);
    a.w = fmaf(s, v.w, a.w);
}

__global__ __launch_bounds__(256) void polnorm_kernel(
    const float* __restrict__ x,        // (B, NIN, 1, 1, NC)
    const float* __restrict__ cx,       // (1, NOUT, 4, 4)
    const float* __restrict__ cy,       // (1, NOUT, 4, 4)
    const float* __restrict__ phis,     // (4,)
    const float* __restrict__ dists_p,  // (4,)
    const float* __restrict__ sigma_p,  // (1,)
    float* __restrict__ out)            // (B, NOUT, 1, 4, 4, 1, NC)
{
    __shared__ __align__(16) float s_w[OPB][NPD][WPAD]; // raw weights, padded rows
    __shared__ float s_inv[OPB][NPD];                   // 1/(sum_ij w + 1e-20)
    __shared__ __align__(16) float s_x[4][NIJ * NC];    // per-wave 2KB x bounce

    const int t = threadIdx.x;
    const int o_base = blockIdx.x * OPB;

    // ---------------- fill phase: w + normalization factors ----------------
    {
        const int pd = t >> 4;        // 0..15
        const int ij = t & 15;        // 0..15
        const int p = pd >> 2, d = pd & 3;

        const float dist = 2.0f / (1.0f + expf(-dists_p[d]));  // 2*sigmoid
        const float phi  = phis[p];
        const float mux  = cosf(phi) * dist;
        const float muy  = sinf(phi) * dist;
        float sg = 2.0f / (1.0f + expf(-sigma_p[0]));
        sg = fmaxf(sg, 1e-10f);
        const float coef = -0.5f / (sg * sg);

        #pragma unroll
        for (int k = 0; k < OPB; ++k) {
            const int o = o_base + k;
            const float dx = cx[o * NIJ + ij] - mux;
            const float dy = cy[o * NIJ + ij] - muy;
            const float w = expf(coef * (dx * dx + dy * dy));
            s_w[k][pd][ij] = w;
            float s = w;                          // reduce over 16 consecutive lanes
            s += __shfl_xor(s, 1);
            s += __shfl_xor(s, 2);
            s += __shfl_xor(s, 4);
            s += __shfl_xor(s, 8);
            if (ij == 0) s_inv[k][pd] = 1.0f / (s + 1e-20f);
        }
    }
    __syncthreads();

    // ---------------- main phase: wave = one b, loop over 4 o ----------------
    const int wid = t >> 6;       // wave id = b
    const int l   = t & 63;       // lane
    const int c4  = l & 7;        // float4 channel slot
    const int pda = l >> 3;       // pd for acc0 (0..7); acc1 uses pda+8

    float4* xs = reinterpret_cast<float4*>(s_x[wid]);   // 128 float4

    const float4* xg = reinterpret_cast<const float4*>(
        x + ((size_t)wid * NIN + (size_t)o_base * NIJ) * NC);      // wave's 8KB
    float4* og = reinterpret_cast<float4*>(
        out + ((size_t)wid * NOUT + o_base) * (size_t)(NPD * NC)); // wave's 8KB

    // prefetch o = 0
    float4 f0 = xg[l];
    float4 f1 = xg[64 + l];

    #pragma unroll
    for (int oi = 0; oi < OPB; ++oi) {
        // stage current o into LDS (same-wave bounce, no barrier needed)
        xs[l] = f0;
        xs[64 + l] = f1;

        // issue next o's loads early (latency hidden under FMA block)
        if (oi + 1 < OPB) {
            f0 = xg[(oi + 1) * 128 + l];
            f1 = xg[(oi + 1) * 128 + 64 + l];
        }

        float4 acc0 = make_float4(0.f, 0.f, 0.f, 0.f);
        float4 acc1 = make_float4(0.f, 0.f, 0.f, 0.f);

        #pragma unroll
        for (int kk = 0; kk < 4; ++kk) {
            const float4 wa = *reinterpret_cast<const float4*>(&s_w[oi][pda][kk * 4]);
            const float4 wb = *reinterpret_cast<const float4*>(&s_w[oi][pda + 8][kk * 4]);
            const float4 xv0 = xs[(kk * 4 + 0) * 8 + c4];
            const float4 xv1 = xs[(kk * 4 + 1) * 8 + c4];
            const float4 xv2 = xs[(kk * 4 + 2) * 8 + c4];
            const float4 xv3 = xs[(kk * 4 + 3) * 8 + c4];
            fma4(acc0, wa.x, xv0); fma4(acc1, wb.x, xv0);
            fma4(acc0, wa.y, xv1); fma4(acc1, wb.y, xv1);
            fma4(acc0, wa.z, xv2); fma4(acc1, wb.z, xv2);
            fma4(acc0, wa.w, xv3); fma4(acc1, wb.w, xv3);
        }

        const float ia = s_inv[oi][pda];
        const float ib = s_inv[oi][pda + 8];
        acc0.x *= ia; acc0.y *= ia; acc0.z *= ia; acc0.w *= ia;
        acc1.x *= ib; acc1.y *= ib; acc1.z *= ib; acc1.w *= ib;

        // stores: float4 idx (pd*8 + c4) == l and 64+l  -> fully contiguous 1KB
        og[oi * 128 + l] = acc0;
        og[oi * 128 + 64 + l] = acc1;
    }
}

} // namespace

extern "C" void kernel_launch(void* const* d_in, const int* in_sizes, int n_in,
                              void* d_out, int out_size, void* d_ws, size_t ws_size,
                              hipStream_t stream) {
    const float* x  = (const float*)d_in[0];
    const float* cx = (const float*)d_in[1];
    const float* cy = (const float*)d_in[2];
    const float* ph = (const float*)d_in[3];
    const float* dp = (const float*)d_in[4];
    const float* sp = (const float*)d_in[5];
    float* out = (float*)d_out;

    dim3 grid(NOUT / OPB);
    dim3 block(256);
    hipLaunchKernelGGL(polnorm_kernel, grid, block, 0, stream,
                       x, cx, cy, ph, dp, sp, out);
}

// Round 7
// 31.739 us; speedup vs baseline: 2.8700x; 1.0348x over previous
//
#include <hip/hip_runtime.h>
#include <math.h>

namespace {

constexpr int NOUT = 10240;
constexpr int OPB  = 4;      // coarse nodes per block
constexpr int NIJ  = 16;     // so*si receptive field
constexpr int NPD  = 16;     // n_phi * n_dist
constexpr int NC   = 32;     // channels
constexpr int NIN  = NOUT * NIJ;
constexpr int WPAD = 20;     // padded ij-stride for s_w (bank-conflict-free float4 reads)

typedef float vfloat4 __attribute__((ext_vector_type(4)));  // native vec for nt-store

__device__ __forceinline__ void fma4(float4& a, float s, const float4& v) {
    a.x = fmaf(s, v.x, a.x);
    a.y = fmaf(s, v.y, a.y);
    a.z = fmaf(s, v.z, a.z);
    a.w = fmaf(s, v.w, a.w);
}

__device__ __forceinline__ void nt_store4(float4* p, const float4& v) {
    vfloat4 nv = { v.x, v.y, v.z, v.w };
    __builtin_nontemporal_store(nv, reinterpret_cast<vfloat4*>(p));
}

__global__ __launch_bounds__(256) void polnorm_kernel(
    const float* __restrict__ x,        // (B, NIN, 1, 1, NC)
    const float* __restrict__ cx,       // (1, NOUT, 4, 4)
    const float* __restrict__ cy,       // (1, NOUT, 4, 4)
    const float* __restrict__ phis,     // (4,)
    const float* __restrict__ dists_p,  // (4,)
    const float* __restrict__ sigma_p,  // (1,)
    float* __restrict__ out)            // (B, NOUT, 1, 4, 4, 1, NC)
{
    __shared__ __align__(16) float s_w[OPB][NPD][WPAD]; // raw weights, padded rows
    __shared__ float s_inv[OPB][NPD];                   // 1/(sum_ij w + 1e-20)
    __shared__ __align__(16) float s_x[4][NIJ * NC];    // per-wave 2KB x bounce

    const int t = threadIdx.x;
    const int o_base = blockIdx.x * OPB;

    const int wid = t >> 6;       // wave id = b
    const int l   = t & 63;       // lane
    const int c4  = l & 7;        // float4 channel slot
    const int pda = l >> 3;       // pd for acc0 (0..7); acc1 uses pda+8

    const float4* xg = reinterpret_cast<const float4*>(
        x + ((size_t)wid * NIN + (size_t)o_base * NIJ) * NC);      // wave's 8KB
    float4* og = reinterpret_cast<float4*>(
        out + ((size_t)wid * NOUT + o_base) * (size_t)(NPD * NC)); // wave's 8KB

    // issue o=0 and o=1 x loads FIRST — latency hides under the fill phase
    float4 f0 = xg[l];
    float4 f1 = xg[64 + l];
    float4 g0 = xg[128 + l];
    float4 g1 = xg[128 + 64 + l];

    // ---------------- fill phase: w + normalization factors ----------------
    {
        const int pd = t >> 4;        // 0..15
        const int ij = t & 15;        // 0..15
        const int p = pd >> 2, d = pd & 3;

        const float dist = 2.0f / (1.0f + expf(-dists_p[d]));  // 2*sigmoid
        const float phi  = phis[p];
        const float mux  = cosf(phi) * dist;
        const float muy  = sinf(phi) * dist;
        float sg = 2.0f / (1.0f + expf(-sigma_p[0]));
        sg = fmaxf(sg, 1e-10f);
        const float coef = -0.5f / (sg * sg);

        #pragma unroll
        for (int k = 0; k < OPB; ++k) {
            const int o = o_base + k;
            const float dx = cx[o * NIJ + ij] - mux;
            const float dy = cy[o * NIJ + ij] - muy;
            const float w = expf(coef * (dx * dx + dy * dy));
            s_w[k][pd][ij] = w;
            float s = w;                          // reduce over 16 consecutive lanes
            s += __shfl_xor(s, 1);
            s += __shfl_xor(s, 2);
            s += __shfl_xor(s, 4);
            s += __shfl_xor(s, 8);
            if (ij == 0) s_inv[k][pd] = 1.0f / (s + 1e-20f);
        }
    }
    __syncthreads();

    // ---------------- main phase: wave = one b, loop over 4 o, 2-deep pipe ----
    float4* xs = reinterpret_cast<float4*>(s_x[wid]);   // 128 float4

    #pragma unroll
    for (int oi = 0; oi < OPB; ++oi) {
        // stage current o into LDS (same-wave bounce, no barrier needed)
        xs[l] = f0;
        xs[64 + l] = f1;

        // rotate pipeline: f <- g, issue o+2's loads into g
        f0 = g0; f1 = g1;
        if (oi + 2 < OPB) {
            g0 = xg[(oi + 2) * 128 + l];
            g1 = xg[(oi + 2) * 128 + 64 + l];
        }

        float4 acc0 = make_float4(0.f, 0.f, 0.f, 0.f);
        float4 acc1 = make_float4(0.f, 0.f, 0.f, 0.f);

        #pragma unroll
        for (int kk = 0; kk < 4; ++kk) {
            const float4 wa = *reinterpret_cast<const float4*>(&s_w[oi][pda][kk * 4]);
            const float4 wb = *reinterpret_cast<const float4*>(&s_w[oi][pda + 8][kk * 4]);
            const float4 xv0 = xs[(kk * 4 + 0) * 8 + c4];
            const float4 xv1 = xs[(kk * 4 + 1) * 8 + c4];
            const float4 xv2 = xs[(kk * 4 + 2) * 8 + c4];
            const float4 xv3 = xs[(kk * 4 + 3) * 8 + c4];
            fma4(acc0, wa.x, xv0); fma4(acc1, wb.x, xv0);
            fma4(acc0, wa.y, xv1); fma4(acc1, wb.y, xv1);
            fma4(acc0, wa.z, xv2); fma4(acc1, wb.z, xv2);
            fma4(acc0, wa.w, xv3); fma4(acc1, wb.w, xv3);
        }

        const float ia = s_inv[oi][pda];
        const float ib = s_inv[oi][pda + 8];
        acc0.x *= ia; acc0.y *= ia; acc0.z *= ia; acc0.w *= ia;
        acc1.x *= ib; acc1.y *= ib; acc1.z *= ib; acc1.w *= ib;

        // streaming stores: output is write-once — keep it out of L2/L3 so x
        // stays cache-resident across timed replays
        nt_store4(&og[oi * 128 + l], acc0);
        nt_store4(&og[oi * 128 + 64 + l], acc1);
    }
}

} // namespace

extern "C" void kernel_launch(void* const* d_in, const int* in_sizes, int n_in,
                              void* d_out, int out_size, void* d_ws, size_t ws_size,
                              hipStream_t stream) {
    const float* x  = (const float*)d_in[0];
    const float* cx = (const float*)d_in[1];
    const float* cy = (const float*)d_in[2];
    const float* ph = (const float*)d_in[3];
    const float* dp = (const float*)d_in[4];
    const float* sp = (const float*)d_in[5];
    float* out = (float*)d_out;

    dim3 grid(NOUT / OPB);
    dim3 block(256);
    hipLaunchKernelGGL(polnorm_kernel, grid, block, 0, stream,
                       x, cx, cy, ph, dp, sp, out);
}